// Round 5
// baseline (424.152 us; speedup 1.0000x reference)
//
#include <hip/hip_runtime.h>
#include <hip/hip_bf16.h>

#define BB 4
#define CC 64
#define HH 256
#define WW 512
#define KCC 32
#define PLANE (HH*WW)

typedef __attribute__((ext_vector_type(8))) __bf16 bf16x8;
typedef __attribute__((ext_vector_type(4))) __bf16 bf16x4;
typedef __attribute__((ext_vector_type(2))) __bf16 bf16x2;
typedef __attribute__((ext_vector_type(4))) float floatx4;

__device__ __forceinline__ float bf2f(unsigned short u) {
    union { unsigned v; float f; } x; x.v = ((unsigned)u) << 16; return x.f;
}

// ===================== Kernel A: projections + BN, layout transform =====================
// v3: 16h x 16w tile (contiguous 1-2KB stores, v2) + deep-MLP staging: all 64
// channel loads hoisted into registers BEFORE any cvt/ds_write, so each wave has
// 64 loads in flight instead of 8 (v2 stalled ~900cy per 8-load batch -> ~45% bus).
__global__ __launch_bounds__(256, 4)
void proj_kernel(const float* __restrict__ x,
                 const float* __restrict__ Wq, const float* __restrict__ Wk,
                 const float* __restrict__ Wv, const float* __restrict__ bv,
                 const float* __restrict__ bnq_g, const float* __restrict__ bnq_b,
                 const float* __restrict__ bnq_m, const float* __restrict__ bnq_v,
                 const float* __restrict__ bnk_g, const float* __restrict__ bnk_b,
                 const float* __restrict__ bnk_m, const float* __restrict__ bnk_v,
                 unsigned short* __restrict__ Qb, unsigned short* __restrict__ Kb,
                 unsigned short* __restrict__ Vb)
{
    __shared__ __align__(16) unsigned short sX[8 * 256 * 8];   // 32 KB  [c8][chunk'][8c]
    __shared__ __align__(16) unsigned short sYQ[16 * 40];      // 1.25 KB
    __shared__ __align__(16) unsigned short sYK[16 * 40];      // 1.25 KB
    __shared__ __align__(16) unsigned short sYV[2][16 * 72];   // 4.5 KB

    const int tid  = threadIdx.x;
    const int lane = tid & 63, wv = tid >> 6;
    const int quad = lane >> 4, lr = lane & 15;
    const int bid  = blockIdx.x;
    const int b = bid >> 9, rem = bid & 511;
    const int h0 = (rem >> 5) << 4;     // 16 h-tiles
    const int w0 = (rem & 31) << 4;     // 32 w-tiles

    // ---- stage x tile: thread (lh, lw), swizzled chunk = lw*16 + (lh^lw) ----
    // All 64 strided loads issued back-to-back into xr[] (64-deep MLP), then
    // converted + packed to LDS.
    {
        const int lw = tid & 15, lh = tid >> 4;
        const float* xb = x + (size_t)b * CC * PLANE + (size_t)(h0 + lh) * WW + w0 + lw;
        const int chs = ((lw << 4) | (lh ^ lw)) * 8;
        float xr[64];
#pragma unroll
        for (int c = 0; c < 64; ++c) xr[c] = xb[(size_t)c * PLANE];
#pragma unroll
        for (int cc = 0; cc < 8; ++cc) {
            bf16x8 v;
#pragma unroll
            for (int j = 0; j < 8; ++j) v[j] = (__bf16)xr[cc * 8 + j];
            *(bf16x8*)&sX[cc * 2048 + chs] = v;
        }
    }

    // ---- per-thread W fragments + BN constants (no LDS tables) ----
    const int nmt = (wv >= 2) ? 4 : 2;
    const float* Wsrc = (wv == 0) ? Wq : (wv == 1) ? Wk : Wv;
    bf16x8 wf[4][2];
#pragma unroll
    for (int mt = 0; mt < 4; ++mt) {
        if (mt >= nmt) break;
#pragma unroll
        for (int ks = 0; ks < 2; ++ks) {
            const float* p = Wsrc + (mt * 16 + lr) * CC + ks * 32 + quad * 8;
            bf16x8 v;
#pragma unroll
            for (int j = 0; j < 8; ++j) v[j] = (__bf16)p[j];
            wf[mt][ks] = v;
        }
    }
    float s8[2][4], b8[4][4];
    if (wv == 0) {
#pragma unroll
        for (int mt = 0; mt < 2; ++mt)
#pragma unroll
            for (int i = 0; i < 4; ++i) {
                int chn = mt * 16 + quad * 4 + i;
                float s = bnq_g[chn] * rsqrtf(bnq_v[chn] + 1e-5f);
                s8[mt][i] = s; b8[mt][i] = bnq_b[chn] - bnq_m[chn] * s;
            }
    } else if (wv == 1) {
#pragma unroll
        for (int mt = 0; mt < 2; ++mt)
#pragma unroll
            for (int i = 0; i < 4; ++i) {
                int chn = mt * 16 + quad * 4 + i;
                float s = bnk_g[chn] * rsqrtf(bnk_v[chn] + 1e-5f);
                s8[mt][i] = s; b8[mt][i] = bnk_b[chn] - bnk_m[chn] * s;
            }
    } else {
#pragma unroll
        for (int mt = 0; mt < 4; ++mt)
#pragma unroll
            for (int i = 0; i < 4; ++i)
                b8[mt][i] = bv[mt * 16 + quad * 4 + i];
    }
    __syncthreads();

    const floatx4 zed = {0.f, 0.f, 0.f, 0.f};

    if (wv < 2) {
        // -------- Q / K: 2 mt x 16 nt, 1KB contiguous stores --------
        unsigned short* sYw = (wv == 0) ? sYQ : sYK;
        unsigned short* Db  = (wv == 0) ? Qb  : Kb;
        const int p2 = lane >> 2, seg = lane & 3;
        for (int nt = 0; nt < 16; ++nt) {
            const int ch = (nt * 16 + (lr ^ nt)) * 8;
            bf16x8 xb0 = *(const bf16x8*)&sX[quad * 2048 + ch];
            bf16x8 xb1 = *(const bf16x8*)&sX[(4 + quad) * 2048 + ch];
#pragma unroll
            for (int mt = 0; mt < 2; ++mt) {
                floatx4 acc = zed;
                acc = __builtin_amdgcn_mfma_f32_16x16x32_bf16(wf[mt][0], xb0, acc, 0, 0, 0);
                acc = __builtin_amdgcn_mfma_f32_16x16x32_bf16(wf[mt][1], xb1, acc, 0, 0, 0);
                bf16x4 y;
#pragma unroll
                for (int i = 0; i < 4; ++i) y[i] = (__bf16)(acc[i] * s8[mt][i] + b8[mt][i]);
                *(bf16x4*)&sYw[lr * 40 + mt * 16 + quad * 4] = y;
            }
            uint4 v = *(const uint4*)&sYw[p2 * 40 + seg * 8];
            *(uint4*)&Db[((size_t)(b * WW + w0 + nt) * HH + h0 + p2) * KCC + seg * 8] = v;
        }
    } else {
        // -------- V: 4 mt (all 64 c) x 8 nt per wave, 2KB contiguous stores --------
        unsigned short* sYw = &sYV[wv - 2][0];
        const int base_nt = (wv - 2) * 8;
        for (int n8 = 0; n8 < 8; ++n8) {
            const int nt = base_nt + n8;
            const int ch = (nt * 16 + (lr ^ nt)) * 8;
            bf16x8 xb0 = *(const bf16x8*)&sX[quad * 2048 + ch];
            bf16x8 xb1 = *(const bf16x8*)&sX[(4 + quad) * 2048 + ch];
#pragma unroll
            for (int mt = 0; mt < 4; ++mt) {
                floatx4 acc = zed;
                acc = __builtin_amdgcn_mfma_f32_16x16x32_bf16(wf[mt][0], xb0, acc, 0, 0, 0);
                acc = __builtin_amdgcn_mfma_f32_16x16x32_bf16(wf[mt][1], xb1, acc, 0, 0, 0);
                bf16x4 y;
#pragma unroll
                for (int i = 0; i < 4; ++i) y[i] = (__bf16)(acc[i] + b8[mt][i]);
                *(bf16x4*)&sYw[lr * 72 + mt * 16 + quad * 4] = y;
            }
            const size_t vbase = ((size_t)(b * WW + w0 + nt) * HH + h0) * CC;
#pragma unroll
            for (int r = 0; r < 2; ++r) {
                int idx = r * 64 + lane;
                int pos = idx >> 3, sg = idx & 7;
                uint4 v = *(const uint4*)&sYw[pos * 72 + sg * 8];
                *(uint4*)&Vb[vbase + pos * CC + sg * 8] = v;
            }
        }
    }
}

// ===================== Kernel B: per-column flash attention, 8 waves =====================
// One block per (b,w) column; wave wv owns query rows h in [32wv, 32wv+32).
// sVf: fragment-major V' -- chunk(g>>3, d) holds V[g..g+7][d] as bf16x8, so every
// main-loop B-frag read is a lane-contiguous 1KB ds_read_b128 (2-way alias = free).
__global__ __launch_bounds__(512, 4)
void attn_kernel(const unsigned short* __restrict__ Qb,
                 const unsigned short* __restrict__ Kb,
                 const unsigned short* __restrict__ Vb,
                 const float* __restrict__ gamma,
                 unsigned short* __restrict__ Ob)
{
    __shared__ __align__(16) unsigned short sVf[16384];   // 32 KB
    __shared__ __align__(16) unsigned short sP[8][1280];  // 20 KB, per-wave P / O-stage
    __shared__ float sL[256];                             // 1 KB

    const int tid = threadIdx.x, lane = tid & 63, wv = tid >> 6;   // wv 0..7
    const int quad = lane >> 4, lr = lane & 15;
    const int col = blockIdx.x;

    const unsigned short* Qg = Qb + (size_t)col * HH * KCC;
    const unsigned short* Kg = Kb + (size_t)col * HH * KCC;
    const unsigned short* Vg = Vb + (size_t)col * HH * CC;

    // Q (B-op) frags: h = wv*32 + ht*16 + lr. K (A-op) frags: all 256 g rows.
    bf16x8 qf[2], kf[16];
#pragma unroll
    for (int ht = 0; ht < 2; ++ht)
        qf[ht] = *(const bf16x8*)&Qg[(wv * 32 + ht * 16 + lr) * KCC + quad * 8];
#pragma unroll
    for (int gt = 0; gt < 16; ++gt)
        kf[gt] = *(const bf16x8*)&Kg[(gt * 16 + lr) * KCC + quad * 8];

    // V -> frag-major sVf, two 128-row halves staged through sVp (aliases sP).
    unsigned short* sVp = &sP[0][0];   // 16 KB staging
    for (int half = 0; half < 2; ++half) {
#pragma unroll
        for (int it = 0; it < 2; ++it) {
            int idx = it * 512 + tid;                 // 1024 x 16B
            int gr = idx >> 3, sg = idx & 7;
            *(uint4*)&sVp[gr * CC + sg * 8] =
                *(const uint4*)&Vg[(size_t)(half * 128 + gr) * CC + sg * 8];
        }
        __syncthreads();
#pragma unroll
        for (int it = 0; it < 2; ++it) {
            int id = it * 512 + tid;                  // 1024 chunks (16 go x 64 d)
            int go = id >> 6, d = id & 63;
            bf16x8 v;
#pragma unroll
            for (int j = 0; j < 8; ++j)
                ((unsigned short*)&v)[j] = sVp[(go * 8 + j) * CC + d];
            *(bf16x8*)&sVf[((half * 16 + go) * 64 + d) * 8] = v;
        }
        __syncthreads();
    }

    floatx4 O[2][4];
#pragma unroll
    for (int a = 0; a < 2; ++a)
#pragma unroll
        for (int dd = 0; dd < 4; ++dd) O[a][dd] = (floatx4){0.f, 0.f, 0.f, 0.f};
    float lpart[2] = {0.f, 0.f};

    unsigned short* sPw = sP[wv];   // [h 32][g 32 pad 40] -- per-wave, no barriers
    const floatx4 zed = {0.f, 0.f, 0.f, 0.f};

#pragma unroll
    for (int ch = 0; ch < 8; ++ch) {
#pragma unroll
        for (int gt = 0; gt < 2; ++gt) {
#pragma unroll
            for (int ht = 0; ht < 2; ++ht) {
                floatx4 s = __builtin_amdgcn_mfma_f32_16x16x32_bf16(kf[ch * 2 + gt], qf[ht], zed, 0, 0, 0);
                float p0 = __expf(s[0]), p1 = __expf(s[1]), p2 = __expf(s[2]), p3 = __expf(s[3]);
                lpart[ht] += (p0 + p1) + (p2 + p3);
                bf16x2 pa = {(__bf16)p0, (__bf16)p1};
                bf16x2 pb = {(__bf16)p2, (__bf16)p3};
                int base = (ht * 16 + lr) * 40 + gt * 16 + quad * 4;
                *(bf16x2*)&sPw[base]     = pa;
                *(bf16x2*)&sPw[base + 2] = pb;
            }
        }
        bf16x8 paf[2];
#pragma unroll
        for (int ht = 0; ht < 2; ++ht)
            paf[ht] = *(const bf16x8*)&sPw[(ht * 16 + lr) * 40 + quad * 8];
#pragma unroll
        for (int dt = 0; dt < 4; ++dt) {
            bf16x8 vf = *(const bf16x8*)&sVf[((ch * 4 + quad) * 64 + dt * 16 + lr) * 8];
#pragma unroll
            for (int ht = 0; ht < 2; ++ht)
                O[ht][dt] = __builtin_amdgcn_mfma_f32_16x16x32_bf16(paf[ht], vf, O[ht][dt], 0, 0, 0);
        }
    }

    const float gm = gamma[0];
#pragma unroll
    for (int ht = 0; ht < 2; ++ht) {
        float l = lpart[ht];
        l += __shfl_xor(l, 16, 64);
        l += __shfl_xor(l, 32, 64);
        if (lane < 16) sL[wv * 32 + ht * 16 + lane] = gm / l;
    }

    // Scale O (C rows h = quad*4+i), stage bf16 per-wave, store coalesced.
#pragma unroll
    for (int ht = 0; ht < 2; ++ht) {
        float f0 = sL[wv * 32 + ht * 16 + quad * 4 + 0];
        float f1 = sL[wv * 32 + ht * 16 + quad * 4 + 1];
        float f2 = sL[wv * 32 + ht * 16 + quad * 4 + 2];
        float f3 = sL[wv * 32 + ht * 16 + quad * 4 + 3];
#pragma unroll
        for (int dt = 0; dt < 4; ++dt) {
            floatx4 o = O[ht][dt];
            int cb = dt * 16 + lr;
            *(__bf16*)&sPw[(quad * 4 + 0) * 72 + cb] = (__bf16)(o[0] * f0);
            *(__bf16*)&sPw[(quad * 4 + 1) * 72 + cb] = (__bf16)(o[1] * f1);
            *(__bf16*)&sPw[(quad * 4 + 2) * 72 + cb] = (__bf16)(o[2] * f2);
            *(__bf16*)&sPw[(quad * 4 + 3) * 72 + cb] = (__bf16)(o[3] * f3);
        }
#pragma unroll
        for (int it = 0; it < 2; ++it) {
            int idx = it * 64 + lane;
            int hr = idx >> 3, sg = idx & 7;
            uint4 v = *(const uint4*)&sPw[hr * 72 + sg * 8];
            *(uint4*)&Ob[(size_t)(col * HH + wv * 32 + ht * 16 + hr) * CC + sg * 8] = v;
        }
    }
}

// ===================== Kernel C: transpose + residual =====================
__global__ __launch_bounds__(256)
void add_kernel(const unsigned short* __restrict__ Ob,
                const float* __restrict__ x,
                float* __restrict__ out)
{
    __shared__ __align__(16) unsigned short sT[64 * 72];
    const int tid = threadIdx.x;
    const int bid = blockIdx.x;
    const int b = bid >> 11, rem = bid & 2047, h = rem >> 3, w0 = (rem & 7) << 6;

#pragma unroll
    for (int it = 0; it < 2; ++it) {
        int idx = it * 256 + tid;
        int tw = idx >> 3, sg = idx & 7;
        uint4 v = *(const uint4*)&Ob[(size_t)((b * WW + w0 + tw) * HH + h) * CC + sg * 8];
        *(uint4*)&sT[tw * 72 + sg * 8] = v;
    }
    __syncthreads();

    const int d = tid >> 2, ws = tid & 3;
    const size_t base = ((size_t)(b * CC + d)) * PLANE + h * WW + w0 + ws * 16;
    const float* xp = x + base;
    float* op = out + base;
#pragma unroll
    for (int k = 0; k < 4; ++k) {
        float4 xv = *(const float4*)&xp[k * 4];
        float4 r;
        r.x = bf2f(sT[(ws * 16 + k * 4 + 0) * 72 + d]) + xv.x;
        r.y = bf2f(sT[(ws * 16 + k * 4 + 1) * 72 + d]) + xv.y;
        r.z = bf2f(sT[(ws * 16 + k * 4 + 2) * 72 + d]) + xv.z;
        r.w = bf2f(sT[(ws * 16 + k * 4 + 3) * 72 + d]) + xv.w;
        *(float4*)&op[k * 4] = r;
    }
}

// ===================== Fallback: fused kernel (if ws too small) =====================
#define KSTR 40
#define VSTR 72
__device__ __forceinline__ float bflo(unsigned u) { union { unsigned v; float f; } x; x.v = u << 16; return x.f; }
__device__ __forceinline__ float bfhi(unsigned u) { union { unsigned v; float f; } x; x.v = u & 0xffff0000u; return x.f; }

__global__ __launch_bounds__(256, 1)
void vattn_fused(const float* __restrict__ x,
                 const float* __restrict__ Wq,
                 const float* __restrict__ bnq_g, const float* __restrict__ bnq_b,
                 const float* __restrict__ bnq_m, const float* __restrict__ bnq_v,
                 const float* __restrict__ Wk,
                 const float* __restrict__ bnk_g, const float* __restrict__ bnk_b,
                 const float* __restrict__ bnk_m, const float* __restrict__ bnk_v,
                 const float* __restrict__ Wv, const float* __restrict__ bv,
                 const float* __restrict__ gamma,
                 float* __restrict__ out)
{
    __shared__ __align__(16) __hip_bfloat16 sK[HH * KSTR];
    __shared__ __align__(16) __hip_bfloat16 sV2[HH * VSTR];
    const int t = threadIdx.x;
    const int bw = blockIdx.x;
    const int b = bw / WW, w = bw % WW;
    const size_t plane = (size_t)HH * WW;
    const float* xp = x + (size_t)b * CC * plane + (size_t)t * WW + w;
    float xr[CC];
#pragma unroll
    for (int c = 0; c < CC; ++c) xr[c] = xp[(size_t)c * plane];
    float qr[KCC];
#pragma unroll
    for (int j = 0; j < KCC; ++j) {
        float aq = 0.f, ak = 0.f;
#pragma unroll
        for (int c = 0; c < CC; ++c) { aq += Wq[j * CC + c] * xr[c]; ak += Wk[j * CC + c] * xr[c]; }
        const float sq = bnq_g[j] * rsqrtf(bnq_v[j] + 1e-5f);
        const float sk = bnk_g[j] * rsqrtf(bnk_v[j] + 1e-5f);
        qr[j] = (aq - bnq_m[j]) * sq + bnq_b[j];
        sK[t * KSTR + j] = __float2bfloat16((ak - bnk_m[j]) * sk + bnk_b[j]);
    }
#pragma unroll
    for (int d = 0; d < CC; ++d) {
        float av = bv[d];
#pragma unroll
        for (int c = 0; c < CC; ++c) av += Wv[d * CC + c] * xr[c];
        sV2[t * VSTR + d] = __float2bfloat16(av);
    }
    __syncthreads();
    float o[CC];
#pragma unroll
    for (int d = 0; d < CC; ++d) o[d] = 0.f;
    float l = 0.f;
    for (int g = 0; g < HH; ++g) {
        const uint4* kp = (const uint4*)(sK + g * KSTR);
        float s = 0.f;
#pragma unroll
        for (int i = 0; i < 4; ++i) {
            const uint4 kk = kp[i];
            s += bflo(kk.x) * qr[i * 8 + 0] + bfhi(kk.x) * qr[i * 8 + 1]
               + bflo(kk.y) * qr[i * 8 + 2] + bfhi(kk.y) * qr[i * 8 + 3]
               + bflo(kk.z) * qr[i * 8 + 4] + bfhi(kk.z) * qr[i * 8 + 5]
               + bflo(kk.w) * qr[i * 8 + 6] + bfhi(kk.w) * qr[i * 8 + 7];
        }
        const float p = __expf(s);
        l += p;
        const uint4* vp = (const uint4*)(sV2 + g * VSTR);
#pragma unroll
        for (int i = 0; i < 8; ++i) {
            const uint4 vv = vp[i];
            o[i * 8 + 0] += p * bflo(vv.x); o[i * 8 + 1] += p * bfhi(vv.x);
            o[i * 8 + 2] += p * bflo(vv.y); o[i * 8 + 3] += p * bfhi(vv.y);
            o[i * 8 + 4] += p * bflo(vv.z); o[i * 8 + 5] += p * bfhi(vv.z);
            o[i * 8 + 6] += p * bflo(vv.w); o[i * 8 + 7] += p * bfhi(vv.w);
        }
    }
    const float gm = gamma[0];
    const float rl = 1.f / l;
    float* op = out + (size_t)b * CC * plane + (size_t)t * WW + w;
#pragma unroll
    for (int d = 0; d < CC; ++d) op[(size_t)d * plane] = gm * (o[d] * rl) + xr[d];
}

extern "C" void kernel_launch(void* const* d_in, const int* in_sizes, int n_in,
                              void* d_out, int out_size, void* d_ws, size_t ws_size,
                              hipStream_t stream) {
    const float* x     = (const float*)d_in[0];
    const float* Wq    = (const float*)d_in[1];
    const float* bnq_g = (const float*)d_in[2];
    const float* bnq_b = (const float*)d_in[3];
    const float* bnq_m = (const float*)d_in[4];
    const float* bnq_v = (const float*)d_in[5];
    const float* Wk    = (const float*)d_in[6];
    const float* bnk_g = (const float*)d_in[7];
    const float* bnk_b = (const float*)d_in[8];
    const float* bnk_m = (const float*)d_in[9];
    const float* bnk_v = (const float*)d_in[10];
    const float* Wv    = (const float*)d_in[11];
    const float* bv    = (const float*)d_in[12];
    const float* gamma = (const float*)d_in[13];
    float* out = (float*)d_out;

    const size_t need = 201326592;   // Qb 32MB + Kb 32MB + Vb 64MB + Ob 64MB
    if (ws_size >= need) {
        unsigned short* Qb = (unsigned short*)d_ws;
        unsigned short* Kb = Qb + 16777216;
        unsigned short* Vb = Kb + 16777216;
        unsigned short* Ob = Vb + 33554432;
        hipLaunchKernelGGL(proj_kernel, dim3(2048), dim3(256), 0, stream,
                           x, Wq, Wk, Wv, bv,
                           bnq_g, bnq_b, bnq_m, bnq_v,
                           bnk_g, bnk_b, bnk_m, bnk_v,
                           Qb, Kb, Vb);
        hipLaunchKernelGGL(attn_kernel, dim3(2048), dim3(512), 0, stream,
                           Qb, Kb, Vb, gamma, Ob);
        hipLaunchKernelGGL(add_kernel, dim3(8192), dim3(256), 0, stream,
                           Ob, x, out);
    } else {
        hipLaunchKernelGGL(vattn_fused, dim3(BB * WW), dim3(HH), 0, stream,
                           x, Wq, bnq_g, bnq_b, bnq_m, bnq_v,
                           Wk, bnk_g, bnk_b, bnk_m, bnk_v,
                           Wv, bv, gamma, out);
    }
}

// Round 6
// 423.573 us; speedup vs baseline: 1.0014x; 1.0014x over previous
//
#include <hip/hip_runtime.h>
#include <hip/hip_bf16.h>

#define BB 4
#define CC 64
#define HH 256
#define WW 512
#define KCC 32
#define PLANE (HH*WW)

typedef __attribute__((ext_vector_type(8))) __bf16 bf16x8;
typedef __attribute__((ext_vector_type(4))) __bf16 bf16x4;
typedef __attribute__((ext_vector_type(2))) __bf16 bf16x2;
typedef __attribute__((ext_vector_type(4))) float floatx4;

__device__ __forceinline__ float bf2f(unsigned short u) {
    union { unsigned v; float f; } x; x.v = ((unsigned)u) << 16; return x.f;
}

__device__ __forceinline__ void async_copy16(const float* gp, float* lp) {
    __builtin_amdgcn_global_load_lds(
        (const __attribute__((address_space(1))) unsigned int*)gp,
        (__attribute__((address_space(3))) unsigned int*)lp,
        16, 0, 0);
}

// ===================== Kernel A: projections + BN, layout transform =====================
// v4: 16h x 16w tile, contiguous 1-2KB stores (v2), staging via global_load_lds:
// two 32-channel passes; each wave issues 8 async 16B/lane copies into a linear
// 32KB f32 buffer (vmcnt queue carries latency -- compiler can't re-sink it, which
// defeated v3's register hoist: VGPR stayed 56). Pack pass converts LDS f32 ->
// swizzled bf16 sX (2-way bank alias on reads = free). sY aliases dead staging.
__global__ __launch_bounds__(256, 2)
void proj_kernel(const float* __restrict__ x,
                 const float* __restrict__ Wq, const float* __restrict__ Wk,
                 const float* __restrict__ Wv, const float* __restrict__ bv,
                 const float* __restrict__ bnq_g, const float* __restrict__ bnq_b,
                 const float* __restrict__ bnq_m, const float* __restrict__ bnq_v,
                 const float* __restrict__ bnk_g, const float* __restrict__ bnk_b,
                 const float* __restrict__ bnk_m, const float* __restrict__ bnk_v,
                 unsigned short* __restrict__ Qb, unsigned short* __restrict__ Kb,
                 unsigned short* __restrict__ Vb)
{
    __shared__ __align__(16) float sStageF[8192];              // 32 KB f32 staging [c32][lh16][lw16]
    __shared__ __align__(16) unsigned short sX[8 * 256 * 8];   // 32 KB  [c8][chunk'][8c]

    // sY buffers alias staging (staging dead after last pack barrier)
    unsigned short* sYQ = (unsigned short*)sStageF;            // 16*40
    unsigned short* sYK = sYQ + 16 * 40;                       // 16*40
    unsigned short* sYVb = sYK + 16 * 40;                      // 2 x 16*72

    const int tid  = threadIdx.x;
    const int lane = tid & 63, wv = tid >> 6;
    const int quad = lane >> 4, lr = lane & 15;
    const int bid  = blockIdx.x;
    const int b = bid >> 9, rem = bid & 511;
    const int h0 = (rem >> 5) << 4;     // 16 h-tiles
    const int w0 = (rem & 31) << 4;     // 32 w-tiles

    const float* xtile = x + (size_t)b * CC * PLANE + (size_t)h0 * WW + w0;
    const int s_lh = lane >> 2, s_ww = lane & 3;   // stage coords: 16 lh x 4 ww quads
    const int p_lw = tid & 15, p_lh = tid >> 4;    // pack coords
    const int chs = ((p_lw << 4) | (p_lh ^ p_lw)) * 8;

    // ---- issue first-half async copies immediately ----
#pragma unroll
    for (int it = 0; it < 8; ++it) {
        const int cl = it * 4 + wv;                 // 0..31
        async_copy16(xtile + (size_t)cl * PLANE + s_lh * WW + s_ww * 4,
                     &sStageF[cl * 256 + lane * 4]);
    }

    // ---- per-thread W fragments + BN constants (overlap with async queue) ----
    const int nmt = (wv >= 2) ? 4 : 2;
    const float* Wsrc = (wv == 0) ? Wq : (wv == 1) ? Wk : Wv;
    bf16x8 wf[4][2];
#pragma unroll
    for (int mt = 0; mt < 4; ++mt) {
        if (mt >= nmt) break;
#pragma unroll
        for (int ks = 0; ks < 2; ++ks) {
            const float* p = Wsrc + (mt * 16 + lr) * CC + ks * 32 + quad * 8;
            bf16x8 v;
#pragma unroll
            for (int j = 0; j < 8; ++j) v[j] = (__bf16)p[j];
            wf[mt][ks] = v;
        }
    }
    float s8[2][4], b8[4][4];
    if (wv == 0) {
#pragma unroll
        for (int mt = 0; mt < 2; ++mt)
#pragma unroll
            for (int i = 0; i < 4; ++i) {
                int chn = mt * 16 + quad * 4 + i;
                float s = bnq_g[chn] * rsqrtf(bnq_v[chn] + 1e-5f);
                s8[mt][i] = s; b8[mt][i] = bnq_b[chn] - bnq_m[chn] * s;
            }
    } else if (wv == 1) {
#pragma unroll
        for (int mt = 0; mt < 2; ++mt)
#pragma unroll
            for (int i = 0; i < 4; ++i) {
                int chn = mt * 16 + quad * 4 + i;
                float s = bnk_g[chn] * rsqrtf(bnk_v[chn] + 1e-5f);
                s8[mt][i] = s; b8[mt][i] = bnk_b[chn] - bnk_m[chn] * s;
            }
    } else {
#pragma unroll
        for (int mt = 0; mt < 4; ++mt)
#pragma unroll
            for (int i = 0; i < 4; ++i)
                b8[mt][i] = bv[mt * 16 + quad * 4 + i];
    }

    // ---- half 0: pack f32 staging -> bf16 sX groups 0..3 ----
    __syncthreads();
#pragma unroll
    for (int cc = 0; cc < 4; ++cc) {
        bf16x8 v;
#pragma unroll
        for (int j = 0; j < 8; ++j)
            v[j] = (__bf16)sStageF[(cc * 8 + j) * 256 + p_lh * 16 + p_lw];
        *(bf16x8*)&sX[cc * 2048 + chs] = v;
    }
    __syncthreads();   // staging reusable

    // ---- half 1: stage channels 32..63, pack -> sX groups 4..7 ----
#pragma unroll
    for (int it = 0; it < 8; ++it) {
        const int cl = it * 4 + wv;
        async_copy16(xtile + (size_t)(32 + cl) * PLANE + s_lh * WW + s_ww * 4,
                     &sStageF[cl * 256 + lane * 4]);
    }
    __syncthreads();
#pragma unroll
    for (int cc = 0; cc < 4; ++cc) {
        bf16x8 v;
#pragma unroll
        for (int j = 0; j < 8; ++j)
            v[j] = (__bf16)sStageF[(cc * 8 + j) * 256 + p_lh * 16 + p_lw];
        *(bf16x8*)&sX[(4 + cc) * 2048 + chs] = v;
    }
    __syncthreads();   // sX complete; staging dead -> sY aliases live from here

    const floatx4 zed = {0.f, 0.f, 0.f, 0.f};

    if (wv < 2) {
        // -------- Q / K: 2 mt x 16 nt, 1KB contiguous stores --------
        unsigned short* sYw = (wv == 0) ? sYQ : sYK;
        unsigned short* Db  = (wv == 0) ? Qb  : Kb;
        const int p2 = lane >> 2, seg = lane & 3;
        for (int nt = 0; nt < 16; ++nt) {
            const int ch = (nt * 16 + (lr ^ nt)) * 8;
            bf16x8 xb0 = *(const bf16x8*)&sX[quad * 2048 + ch];
            bf16x8 xb1 = *(const bf16x8*)&sX[(4 + quad) * 2048 + ch];
#pragma unroll
            for (int mt = 0; mt < 2; ++mt) {
                floatx4 acc = zed;
                acc = __builtin_amdgcn_mfma_f32_16x16x32_bf16(wf[mt][0], xb0, acc, 0, 0, 0);
                acc = __builtin_amdgcn_mfma_f32_16x16x32_bf16(wf[mt][1], xb1, acc, 0, 0, 0);
                bf16x4 y;
#pragma unroll
                for (int i = 0; i < 4; ++i) y[i] = (__bf16)(acc[i] * s8[mt][i] + b8[mt][i]);
                *(bf16x4*)&sYw[lr * 40 + mt * 16 + quad * 4] = y;
            }
            uint4 v = *(const uint4*)&sYw[p2 * 40 + seg * 8];
            *(uint4*)&Db[((size_t)(b * WW + w0 + nt) * HH + h0 + p2) * KCC + seg * 8] = v;
        }
    } else {
        // -------- V: 4 mt (all 64 c) x 8 nt per wave, 2KB contiguous stores --------
        unsigned short* sYw = sYVb + (wv - 2) * (16 * 72);
        const int base_nt = (wv - 2) * 8;
        for (int n8 = 0; n8 < 8; ++n8) {
            const int nt = base_nt + n8;
            const int ch = (nt * 16 + (lr ^ nt)) * 8;
            bf16x8 xb0 = *(const bf16x8*)&sX[quad * 2048 + ch];
            bf16x8 xb1 = *(const bf16x8*)&sX[(4 + quad) * 2048 + ch];
#pragma unroll
            for (int mt = 0; mt < 4; ++mt) {
                floatx4 acc = zed;
                acc = __builtin_amdgcn_mfma_f32_16x16x32_bf16(wf[mt][0], xb0, acc, 0, 0, 0);
                acc = __builtin_amdgcn_mfma_f32_16x16x32_bf16(wf[mt][1], xb1, acc, 0, 0, 0);
                bf16x4 y;
#pragma unroll
                for (int i = 0; i < 4; ++i) y[i] = (__bf16)(acc[i] + b8[mt][i]);
                *(bf16x4*)&sYw[lr * 72 + mt * 16 + quad * 4] = y;
            }
            const size_t vbase = ((size_t)(b * WW + w0 + nt) * HH + h0) * CC;
#pragma unroll
            for (int r = 0; r < 2; ++r) {
                int idx = r * 64 + lane;
                int pos = idx >> 3, sg = idx & 7;
                uint4 v = *(const uint4*)&sYw[pos * 72 + sg * 8];
                *(uint4*)&Vb[vbase + pos * CC + sg * 8] = v;
            }
        }
    }
}

// ===================== Kernel B: per-column flash attention, 8 waves =====================
// One block per (b,w) column; wave wv owns query rows h in [32wv, 32wv+32).
// sVf: fragment-major V' -- chunk(g>>3, d) holds V[g..g+7][d] as bf16x8, so every
// main-loop B-frag read is a lane-contiguous 1KB ds_read_b128 (2-way alias = free).
__global__ __launch_bounds__(512, 4)
void attn_kernel(const unsigned short* __restrict__ Qb,
                 const unsigned short* __restrict__ Kb,
                 const unsigned short* __restrict__ Vb,
                 const float* __restrict__ gamma,
                 unsigned short* __restrict__ Ob)
{
    __shared__ __align__(16) unsigned short sVf[16384];   // 32 KB
    __shared__ __align__(16) unsigned short sP[8][1280];  // 20 KB, per-wave P / O-stage
    __shared__ float sL[256];                             // 1 KB

    const int tid = threadIdx.x, lane = tid & 63, wv = tid >> 6;   // wv 0..7
    const int quad = lane >> 4, lr = lane & 15;
    const int col = blockIdx.x;

    const unsigned short* Qg = Qb + (size_t)col * HH * KCC;
    const unsigned short* Kg = Kb + (size_t)col * HH * KCC;
    const unsigned short* Vg = Vb + (size_t)col * HH * CC;

    // Q (B-op) frags: h = wv*32 + ht*16 + lr. K (A-op) frags: all 256 g rows.
    bf16x8 qf[2], kf[16];
#pragma unroll
    for (int ht = 0; ht < 2; ++ht)
        qf[ht] = *(const bf16x8*)&Qg[(wv * 32 + ht * 16 + lr) * KCC + quad * 8];
#pragma unroll
    for (int gt = 0; gt < 16; ++gt)
        kf[gt] = *(const bf16x8*)&Kg[(gt * 16 + lr) * KCC + quad * 8];

    // V -> frag-major sVf, two 128-row halves staged through sVp (aliases sP).
    unsigned short* sVp = &sP[0][0];   // 16 KB staging
    for (int half = 0; half < 2; ++half) {
#pragma unroll
        for (int it = 0; it < 2; ++it) {
            int idx = it * 512 + tid;                 // 1024 x 16B
            int gr = idx >> 3, sg = idx & 7;
            *(uint4*)&sVp[gr * CC + sg * 8] =
                *(const uint4*)&Vg[(size_t)(half * 128 + gr) * CC + sg * 8];
        }
        __syncthreads();
#pragma unroll
        for (int it = 0; it < 2; ++it) {
            int id = it * 512 + tid;                  // 1024 chunks (16 go x 64 d)
            int go = id >> 6, d = id & 63;
            bf16x8 v;
#pragma unroll
            for (int j = 0; j < 8; ++j)
                ((unsigned short*)&v)[j] = sVp[(go * 8 + j) * CC + d];
            *(bf16x8*)&sVf[((half * 16 + go) * 64 + d) * 8] = v;
        }
        __syncthreads();
    }

    floatx4 O[2][4];
#pragma unroll
    for (int a = 0; a < 2; ++a)
#pragma unroll
        for (int dd = 0; dd < 4; ++dd) O[a][dd] = (floatx4){0.f, 0.f, 0.f, 0.f};
    float lpart[2] = {0.f, 0.f};

    unsigned short* sPw = sP[wv];   // [h 32][g 32 pad 40] -- per-wave, no barriers
    const floatx4 zed = {0.f, 0.f, 0.f, 0.f};

#pragma unroll
    for (int ch = 0; ch < 8; ++ch) {
#pragma unroll
        for (int gt = 0; gt < 2; ++gt) {
#pragma unroll
            for (int ht = 0; ht < 2; ++ht) {
                floatx4 s = __builtin_amdgcn_mfma_f32_16x16x32_bf16(kf[ch * 2 + gt], qf[ht], zed, 0, 0, 0);
                float p0 = __expf(s[0]), p1 = __expf(s[1]), p2 = __expf(s[2]), p3 = __expf(s[3]);
                lpart[ht] += (p0 + p1) + (p2 + p3);
                bf16x2 pa = {(__bf16)p0, (__bf16)p1};
                bf16x2 pb = {(__bf16)p2, (__bf16)p3};
                int base = (ht * 16 + lr) * 40 + gt * 16 + quad * 4;
                *(bf16x2*)&sPw[base]     = pa;
                *(bf16x2*)&sPw[base + 2] = pb;
            }
        }
        bf16x8 paf[2];
#pragma unroll
        for (int ht = 0; ht < 2; ++ht)
            paf[ht] = *(const bf16x8*)&sPw[(ht * 16 + lr) * 40 + quad * 8];
#pragma unroll
        for (int dt = 0; dt < 4; ++dt) {
            bf16x8 vf = *(const bf16x8*)&sVf[((ch * 4 + quad) * 64 + dt * 16 + lr) * 8];
#pragma unroll
            for (int ht = 0; ht < 2; ++ht)
                O[ht][dt] = __builtin_amdgcn_mfma_f32_16x16x32_bf16(paf[ht], vf, O[ht][dt], 0, 0, 0);
        }
    }

    const float gm = gamma[0];
#pragma unroll
    for (int ht = 0; ht < 2; ++ht) {
        float l = lpart[ht];
        l += __shfl_xor(l, 16, 64);
        l += __shfl_xor(l, 32, 64);
        if (lane < 16) sL[wv * 32 + ht * 16 + lane] = gm / l;
    }

    // Scale O (C rows h = quad*4+i), stage bf16 per-wave, store coalesced.
#pragma unroll
    for (int ht = 0; ht < 2; ++ht) {
        float f0 = sL[wv * 32 + ht * 16 + quad * 4 + 0];
        float f1 = sL[wv * 32 + ht * 16 + quad * 4 + 1];
        float f2 = sL[wv * 32 + ht * 16 + quad * 4 + 2];
        float f3 = sL[wv * 32 + ht * 16 + quad * 4 + 3];
#pragma unroll
        for (int dt = 0; dt < 4; ++dt) {
            floatx4 o = O[ht][dt];
            int cb = dt * 16 + lr;
            *(__bf16*)&sPw[(quad * 4 + 0) * 72 + cb] = (__bf16)(o[0] * f0);
            *(__bf16*)&sPw[(quad * 4 + 1) * 72 + cb] = (__bf16)(o[1] * f1);
            *(__bf16*)&sPw[(quad * 4 + 2) * 72 + cb] = (__bf16)(o[2] * f2);
            *(__bf16*)&sPw[(quad * 4 + 3) * 72 + cb] = (__bf16)(o[3] * f3);
        }
#pragma unroll
        for (int it = 0; it < 2; ++it) {
            int idx = it * 64 + lane;
            int hr = idx >> 3, sg = idx & 7;
            uint4 v = *(const uint4*)&sPw[hr * 72 + sg * 8];
            *(uint4*)&Ob[(size_t)(col * HH + wv * 32 + ht * 16 + hr) * CC + sg * 8] = v;
        }
    }
}

// ===================== Kernel C: transpose + residual =====================
__global__ __launch_bounds__(256)
void add_kernel(const unsigned short* __restrict__ Ob,
                const float* __restrict__ x,
                float* __restrict__ out)
{
    __shared__ __align__(16) unsigned short sT[64 * 72];
    const int tid = threadIdx.x;
    const int bid = blockIdx.x;
    const int b = bid >> 11, rem = bid & 2047, h = rem >> 3, w0 = (rem & 7) << 6;

#pragma unroll
    for (int it = 0; it < 2; ++it) {
        int idx = it * 256 + tid;
        int tw = idx >> 3, sg = idx & 7;
        uint4 v = *(const uint4*)&Ob[(size_t)((b * WW + w0 + tw) * HH + h) * CC + sg * 8];
        *(uint4*)&sT[tw * 72 + sg * 8] = v;
    }
    __syncthreads();

    const int d = tid >> 2, ws = tid & 3;
    const size_t base = ((size_t)(b * CC + d)) * PLANE + h * WW + w0 + ws * 16;
    const float* xp = x + base;
    float* op = out + base;
#pragma unroll
    for (int k = 0; k < 4; ++k) {
        float4 xv = *(const float4*)&xp[k * 4];
        float4 r;
        r.x = bf2f(sT[(ws * 16 + k * 4 + 0) * 72 + d]) + xv.x;
        r.y = bf2f(sT[(ws * 16 + k * 4 + 1) * 72 + d]) + xv.y;
        r.z = bf2f(sT[(ws * 16 + k * 4 + 2) * 72 + d]) + xv.z;
        r.w = bf2f(sT[(ws * 16 + k * 4 + 3) * 72 + d]) + xv.w;
        *(float4*)&op[k * 4] = r;
    }
}

// ===================== Fallback: fused kernel (if ws too small) =====================
#define KSTR 40
#define VSTR 72
__device__ __forceinline__ float bflo(unsigned u) { union { unsigned v; float f; } x; x.v = u << 16; return x.f; }
__device__ __forceinline__ float bfhi(unsigned u) { union { unsigned v; float f; } x; x.v = u & 0xffff0000u; return x.f; }

__global__ __launch_bounds__(256, 1)
void vattn_fused(const float* __restrict__ x,
                 const float* __restrict__ Wq,
                 const float* __restrict__ bnq_g, const float* __restrict__ bnq_b,
                 const float* __restrict__ bnq_m, const float* __restrict__ bnq_v,
                 const float* __restrict__ Wk,
                 const float* __restrict__ bnk_g, const float* __restrict__ bnk_b,
                 const float* __restrict__ bnk_m, const float* __restrict__ bnk_v,
                 const float* __restrict__ Wv, const float* __restrict__ bv,
                 const float* __restrict__ gamma,
                 float* __restrict__ out)
{
    __shared__ __align__(16) __hip_bfloat16 sK[HH * KSTR];
    __shared__ __align__(16) __hip_bfloat16 sV2[HH * VSTR];
    const int t = threadIdx.x;
    const int bw = blockIdx.x;
    const int b = bw / WW, w = bw % WW;
    const size_t plane = (size_t)HH * WW;
    const float* xp = x + (size_t)b * CC * plane + (size_t)t * WW + w;
    float xr[CC];
#pragma unroll
    for (int c = 0; c < CC; ++c) xr[c] = xp[(size_t)c * plane];
    float qr[KCC];
#pragma unroll
    for (int j = 0; j < KCC; ++j) {
        float aq = 0.f, ak = 0.f;
#pragma unroll
        for (int c = 0; c < CC; ++c) { aq += Wq[j * CC + c] * xr[c]; ak += Wk[j * CC + c] * xr[c]; }
        const float sq = bnq_g[j] * rsqrtf(bnq_v[j] + 1e-5f);
        const float sk = bnk_g[j] * rsqrtf(bnk_v[j] + 1e-5f);
        qr[j] = (aq - bnq_m[j]) * sq + bnq_b[j];
        sK[t * KSTR + j] = __float2bfloat16((ak - bnk_m[j]) * sk + bnk_b[j]);
    }
#pragma unroll
    for (int d = 0; d < CC; ++d) {
        float av = bv[d];
#pragma unroll
        for (int c = 0; c < CC; ++c) av += Wv[d * CC + c] * xr[c];
        sV2[t * VSTR + d] = __float2bfloat16(av);
    }
    __syncthreads();
    float o[CC];
#pragma unroll
    for (int d = 0; d < CC; ++d) o[d] = 0.f;
    float l = 0.f;
    for (int g = 0; g < HH; ++g) {
        const uint4* kp = (const uint4*)(sK + g * KSTR);
        float s = 0.f;
#pragma unroll
        for (int i = 0; i < 4; ++i) {
            const uint4 kk = kp[i];
            s += bflo(kk.x) * qr[i * 8 + 0] + bfhi(kk.x) * qr[i * 8 + 1]
               + bflo(kk.y) * qr[i * 8 + 2] + bfhi(kk.y) * qr[i * 8 + 3]
               + bflo(kk.z) * qr[i * 8 + 4] + bfhi(kk.z) * qr[i * 8 + 5]
               + bflo(kk.w) * qr[i * 8 + 6] + bfhi(kk.w) * qr[i * 8 + 7];
        }
        const float p = __expf(s);
        l += p;
        const uint4* vp = (const uint4*)(sV2 + g * VSTR);
#pragma unroll
        for (int i = 0; i < 8; ++i) {
            const uint4 vv = vp[i];
            o[i * 8 + 0] += p * bflo(vv.x); o[i * 8 + 1] += p * bfhi(vv.x);
            o[i * 8 + 2] += p * bflo(vv.y); o[i * 8 + 3] += p * bfhi(vv.y);
            o[i * 8 + 4] += p * bflo(vv.z); o[i * 8 + 5] += p * bfhi(vv.z);
            o[i * 8 + 6] += p * bflo(vv.w); o[i * 8 + 7] += p * bfhi(vv.w);
        }
    }
    const float gm = gamma[0];
    const float rl = 1.f / l;
    float* op = out + (size_t)b * CC * plane + (size_t)t * WW + w;
#pragma unroll
    for (int d = 0; d < CC; ++d) op[(size_t)d * plane] = gm * (o[d] * rl) + xr[d];
}

extern "C" void kernel_launch(void* const* d_in, const int* in_sizes, int n_in,
                              void* d_out, int out_size, void* d_ws, size_t ws_size,
                              hipStream_t stream) {
    const float* x     = (const float*)d_in[0];
    const float* Wq    = (const float*)d_in[1];
    const float* bnq_g = (const float*)d_in[2];
    const float* bnq_b = (const float*)d_in[3];
    const float* bnq_m = (const float*)d_in[4];
    const float* bnq_v = (const float*)d_in[5];
    const float* Wk    = (const float*)d_in[6];
    const float* bnk_g = (const float*)d_in[7];
    const float* bnk_b = (const float*)d_in[8];
    const float* bnk_m = (const float*)d_in[9];
    const float* bnk_v = (const float*)d_in[10];
    const float* Wv    = (const float*)d_in[11];
    const float* bv    = (const float*)d_in[12];
    const float* gamma = (const float*)d_in[13];
    float* out = (float*)d_out;

    const size_t need = 201326592;   // Qb 32MB + Kb 32MB + Vb 64MB + Ob 64MB
    if (ws_size >= need) {
        unsigned short* Qb = (unsigned short*)d_ws;
        unsigned short* Kb = Qb + 16777216;
        unsigned short* Vb = Kb + 16777216;
        unsigned short* Ob = Vb + 33554432;
        hipLaunchKernelGGL(proj_kernel, dim3(2048), dim3(256), 0, stream,
                           x, Wq, Wk, Wv, bv,
                           bnq_g, bnq_b, bnq_m, bnq_v,
                           bnk_g, bnk_b, bnk_m, bnk_v,
                           Qb, Kb, Vb);
        hipLaunchKernelGGL(attn_kernel, dim3(2048), dim3(512), 0, stream,
                           Qb, Kb, Vb, gamma, Ob);
        hipLaunchKernelGGL(add_kernel, dim3(8192), dim3(256), 0, stream,
                           Ob, x, out);
    } else {
        hipLaunchKernelGGL(vattn_fused, dim3(BB * WW), dim3(HH), 0, stream,
                           x, Wq, bnq_g, bnq_b, bnq_m, bnq_v,
                           Wk, bnk_g, bnk_b, bnk_m, bnk_v,
                           Wv, bv, gamma, out);
    }
}

// Round 7
// 414.003 us; speedup vs baseline: 1.0245x; 1.0231x over previous
//
#include <hip/hip_runtime.h>
#include <hip/hip_bf16.h>

#define BB 4
#define CC 64
#define HH 256
#define WW 512
#define KCC 32
#define PLANE (HH*WW)

typedef __attribute__((ext_vector_type(8))) __bf16 bf16x8;
typedef __attribute__((ext_vector_type(4))) __bf16 bf16x4;
typedef __attribute__((ext_vector_type(2))) __bf16 bf16x2;
typedef __attribute__((ext_vector_type(4))) float floatx4;

__device__ __forceinline__ float bf2f(unsigned short u) {
    union { unsigned v; float f; } x; x.v = ((unsigned)u) << 16; return x.f;
}

__device__ __forceinline__ void async_copy16(const float* gp, float* lp) {
    __builtin_amdgcn_global_load_lds(
        (const __attribute__((address_space(1))) unsigned int*)gp,
        (__attribute__((address_space(3))) unsigned int*)lp,
        16, 0, 0);
}

// ===================== Kernel A: projections + BN, layout transform =====================
// v5: tile-level software pipeline. Each block (512 thr, 8 waves) owns 4 tiles of
// 16h x 16w. While tile t computes+stores, the async global_load_lds queue fills
// stageF with tile t+1 -> HBM reads flow DURING the write phase (v2-v4 alternated
// read-burst/write-burst in lockstep across blocks, capping the bus at ~50% =
// measured 2.75 TB/s regardless of staging mechanism). LDS 114KB -> 1 block/CU.
// Waves: 0,1=Q(nt 0-7/8-15) 2,3=K 4..7=V(nt 4 each, all 64c).
__global__ __launch_bounds__(512, 1)
void proj_kernel(const float* __restrict__ x,
                 const float* __restrict__ Wq, const float* __restrict__ Wk,
                 const float* __restrict__ Wv, const float* __restrict__ bv,
                 const float* __restrict__ bnq_g, const float* __restrict__ bnq_b,
                 const float* __restrict__ bnq_m, const float* __restrict__ bnq_v,
                 const float* __restrict__ bnk_g, const float* __restrict__ bnk_b,
                 const float* __restrict__ bnk_m, const float* __restrict__ bnk_v,
                 unsigned short* __restrict__ Qb, unsigned short* __restrict__ Kb,
                 unsigned short* __restrict__ Vb)
{
    __shared__ __align__(16) float sStageF[64 * 256];          // 64 KB [c64][16h*16w]
    __shared__ __align__(16) unsigned short sX[8 * 256 * 8];   // 32 KB [c8][chunk'][8c]
    __shared__ __align__(16) unsigned short sY[8][16 * 72];    // 18 KB per-wave stage

    const int tid  = threadIdx.x;
    const int lane = tid & 63, wv = tid >> 6;                  // 8 waves
    const int quad = lane >> 4, lr = lane & 15;
    const int s_lh = lane >> 2, s_ww = lane & 3;               // stage coords
    const int pos  = tid & 255, phalf = tid >> 8;              // pack coords
    const int p_lw = pos & 15, p_lh = pos >> 4;
    const int chs  = ((p_lw << 4) | (p_lh ^ p_lw)) * 8;

    // ---- per-wave W fragments + BN constants (overlap with first stage flight) ----
    const int nmt = (wv >= 4) ? 4 : 2;
    const float* Wsrc = (wv < 2) ? Wq : (wv < 4) ? Wk : Wv;

    // issue stage(tile 0) first so the queue fills while we read W/BN
    {
        const int gt0 = blockIdx.x * 4;
        const int b = gt0 >> 9, rem = gt0 & 511;
        const float* xg = x + (size_t)b * CC * PLANE
                        + (size_t)((rem >> 5) << 4) * WW + ((rem & 31) << 4);
#pragma unroll
        for (int it = 0; it < 8; ++it) {
            const int cl = it * 8 + wv;
            async_copy16(xg + (size_t)cl * PLANE + s_lh * WW + s_ww * 4,
                         &sStageF[cl * 256 + lane * 4]);
        }
    }

    bf16x8 wf[4][2];
#pragma unroll
    for (int mt = 0; mt < 4; ++mt) {
        if (mt >= nmt) break;
#pragma unroll
        for (int ks = 0; ks < 2; ++ks) {
            const float* p = Wsrc + (mt * 16 + lr) * CC + ks * 32 + quad * 8;
            bf16x8 v;
#pragma unroll
            for (int j = 0; j < 8; ++j) v[j] = (__bf16)p[j];
            wf[mt][ks] = v;
        }
    }
    float s8[2][4], b8[4][4];
    if (wv < 2) {
#pragma unroll
        for (int mt = 0; mt < 2; ++mt)
#pragma unroll
            for (int i = 0; i < 4; ++i) {
                int chn = mt * 16 + quad * 4 + i;
                float s = bnq_g[chn] * rsqrtf(bnq_v[chn] + 1e-5f);
                s8[mt][i] = s; b8[mt][i] = bnq_b[chn] - bnq_m[chn] * s;
            }
    } else if (wv < 4) {
#pragma unroll
        for (int mt = 0; mt < 2; ++mt)
#pragma unroll
            for (int i = 0; i < 4; ++i) {
                int chn = mt * 16 + quad * 4 + i;
                float s = bnk_g[chn] * rsqrtf(bnk_v[chn] + 1e-5f);
                s8[mt][i] = s; b8[mt][i] = bnk_b[chn] - bnk_m[chn] * s;
            }
    } else {
#pragma unroll
        for (int mt = 0; mt < 4; ++mt)
#pragma unroll
            for (int i = 0; i < 4; ++i)
                b8[mt][i] = bv[mt * 16 + quad * 4 + i];
    }

    const floatx4 zed = {0.f, 0.f, 0.f, 0.f};
    unsigned short* sYw = sY[wv];
    const int p2 = lane >> 2, seg = lane & 3;

    for (int t = 0; t < 4; ++t) {
        const int gt = blockIdx.x * 4 + t;
        const int b = gt >> 9, rem = gt & 511;
        const int h0 = (rem >> 5) << 4, w0 = (rem & 31) << 4;

        __syncthreads();   // vmcnt(0) drained before barrier -> stage(t) landed

        // ---- pack stageF f32 -> swizzled bf16 sX (each thread: 4 groups) ----
#pragma unroll
        for (int cc = 0; cc < 4; ++cc) {
            const int g = phalf * 4 + cc;
            bf16x8 v;
#pragma unroll
            for (int j = 0; j < 8; ++j)
                v[j] = (__bf16)sStageF[(g * 8 + j) * 256 + p_lh * 16 + p_lw];
            *(bf16x8*)&sX[g * 2048 + chs] = v;
        }
        __syncthreads();   // sX ready, stageF free for tile t+1

        // ---- issue async stage(t+1): reads fly under the compute/store below ----
        if (t < 3) {
            const int gt1 = gt + 1;
            const int b1 = gt1 >> 9, rem1 = gt1 & 511;
            const float* xg = x + (size_t)b1 * CC * PLANE
                            + (size_t)((rem1 >> 5) << 4) * WW + ((rem1 & 31) << 4);
#pragma unroll
            for (int it = 0; it < 8; ++it) {
                const int cl = it * 8 + wv;
                async_copy16(xg + (size_t)cl * PLANE + s_lh * WW + s_ww * 4,
                             &sStageF[cl * 256 + lane * 4]);
            }
        }

        // ---- compute + store tile t ----
        if (wv < 4) {
            // Q or K: 8 nt x 2 mt, 1KB contiguous stores
            unsigned short* Db = (wv < 2) ? Qb : Kb;
            const int ntb = (wv & 1) << 3;
#pragma unroll
            for (int i = 0; i < 8; ++i) {
                const int nt = ntb + i;
                const int ch = (nt * 16 + (lr ^ nt)) * 8;
                bf16x8 xb0 = *(const bf16x8*)&sX[quad * 2048 + ch];
                bf16x8 xb1 = *(const bf16x8*)&sX[(4 + quad) * 2048 + ch];
#pragma unroll
                for (int mt = 0; mt < 2; ++mt) {
                    floatx4 acc = zed;
                    acc = __builtin_amdgcn_mfma_f32_16x16x32_bf16(wf[mt][0], xb0, acc, 0, 0, 0);
                    acc = __builtin_amdgcn_mfma_f32_16x16x32_bf16(wf[mt][1], xb1, acc, 0, 0, 0);
                    bf16x4 y;
#pragma unroll
                    for (int k = 0; k < 4; ++k) y[k] = (__bf16)(acc[k] * s8[mt][k] + b8[mt][k]);
                    *(bf16x4*)&sYw[lr * 72 + mt * 16 + quad * 4] = y;
                }
                uint4 v = *(const uint4*)&sYw[p2 * 72 + seg * 8];
                *(uint4*)&Db[((size_t)(b * WW + w0 + nt) * HH + h0 + p2) * KCC + seg * 8] = v;
            }
        } else {
            // V: 4 nt x 4 mt (all 64c), 2KB contiguous stores
            const int ntb = (wv - 4) << 2;
#pragma unroll
            for (int i = 0; i < 4; ++i) {
                const int nt = ntb + i;
                const int ch = (nt * 16 + (lr ^ nt)) * 8;
                bf16x8 xb0 = *(const bf16x8*)&sX[quad * 2048 + ch];
                bf16x8 xb1 = *(const bf16x8*)&sX[(4 + quad) * 2048 + ch];
#pragma unroll
                for (int mt = 0; mt < 4; ++mt) {
                    floatx4 acc = zed;
                    acc = __builtin_amdgcn_mfma_f32_16x16x32_bf16(wf[mt][0], xb0, acc, 0, 0, 0);
                    acc = __builtin_amdgcn_mfma_f32_16x16x32_bf16(wf[mt][1], xb1, acc, 0, 0, 0);
                    bf16x4 y;
#pragma unroll
                    for (int k = 0; k < 4; ++k) y[k] = (__bf16)(acc[k] + b8[mt][k]);
                    *(bf16x4*)&sYw[lr * 72 + mt * 16 + quad * 4] = y;
                }
                const size_t vbase = ((size_t)(b * WW + w0 + nt) * HH + h0) * CC;
#pragma unroll
                for (int r = 0; r < 2; ++r) {
                    int idx = r * 64 + lane;
                    int ps = idx >> 3, sg = idx & 7;
                    uint4 v = *(const uint4*)&sYw[ps * 72 + sg * 8];
                    *(uint4*)&Vb[vbase + ps * CC + sg * 8] = v;
                }
            }
        }
    }
}

// ===================== Kernel B: per-column flash attention, 8 waves =====================
// One block per (b,w) column; wave wv owns query rows h in [32wv, 32wv+32).
// sVf: fragment-major V' -- chunk(g>>3, d) holds V[g..g+7][d] as bf16x8, so every
// main-loop B-frag read is a lane-contiguous 1KB ds_read_b128 (2-way alias = free).
__global__ __launch_bounds__(512, 4)
void attn_kernel(const unsigned short* __restrict__ Qb,
                 const unsigned short* __restrict__ Kb,
                 const unsigned short* __restrict__ Vb,
                 const float* __restrict__ gamma,
                 unsigned short* __restrict__ Ob)
{
    __shared__ __align__(16) unsigned short sVf[16384];   // 32 KB
    __shared__ __align__(16) unsigned short sP[8][1280];  // 20 KB, per-wave P / O-stage
    __shared__ float sL[256];                             // 1 KB

    const int tid = threadIdx.x, lane = tid & 63, wv = tid >> 6;   // wv 0..7
    const int quad = lane >> 4, lr = lane & 15;
    const int col = blockIdx.x;

    const unsigned short* Qg = Qb + (size_t)col * HH * KCC;
    const unsigned short* Kg = Kb + (size_t)col * HH * KCC;
    const unsigned short* Vg = Vb + (size_t)col * HH * CC;

    // Q (B-op) frags: h = wv*32 + ht*16 + lr. K (A-op) frags: all 256 g rows.
    bf16x8 qf[2], kf[16];
#pragma unroll
    for (int ht = 0; ht < 2; ++ht)
        qf[ht] = *(const bf16x8*)&Qg[(wv * 32 + ht * 16 + lr) * KCC + quad * 8];
#pragma unroll
    for (int gt = 0; gt < 16; ++gt)
        kf[gt] = *(const bf16x8*)&Kg[(gt * 16 + lr) * KCC + quad * 8];

    // V -> frag-major sVf, two 128-row halves staged through sVp (aliases sP).
    unsigned short* sVp = &sP[0][0];   // 16 KB staging
    for (int half = 0; half < 2; ++half) {
#pragma unroll
        for (int it = 0; it < 2; ++it) {
            int idx = it * 512 + tid;                 // 1024 x 16B
            int gr = idx >> 3, sg = idx & 7;
            *(uint4*)&sVp[gr * CC + sg * 8] =
                *(const uint4*)&Vg[(size_t)(half * 128 + gr) * CC + sg * 8];
        }
        __syncthreads();
#pragma unroll
        for (int it = 0; it < 2; ++it) {
            int id = it * 512 + tid;                  // 1024 chunks (16 go x 64 d)
            int go = id >> 6, d = id & 63;
            bf16x8 v;
#pragma unroll
            for (int j = 0; j < 8; ++j)
                ((unsigned short*)&v)[j] = sVp[(go * 8 + j) * CC + d];
            *(bf16x8*)&sVf[((half * 16 + go) * 64 + d) * 8] = v;
        }
        __syncthreads();
    }

    floatx4 O[2][4];
#pragma unroll
    for (int a = 0; a < 2; ++a)
#pragma unroll
        for (int dd = 0; dd < 4; ++dd) O[a][dd] = (floatx4){0.f, 0.f, 0.f, 0.f};
    float lpart[2] = {0.f, 0.f};

    unsigned short* sPw = sP[wv];   // [h 32][g 32 pad 40] -- per-wave, no barriers
    const floatx4 zed = {0.f, 0.f, 0.f, 0.f};

#pragma unroll
    for (int ch = 0; ch < 8; ++ch) {
#pragma unroll
        for (int gt = 0; gt < 2; ++gt) {
#pragma unroll
            for (int ht = 0; ht < 2; ++ht) {
                floatx4 s = __builtin_amdgcn_mfma_f32_16x16x32_bf16(kf[ch * 2 + gt], qf[ht], zed, 0, 0, 0);
                float p0 = __expf(s[0]), p1 = __expf(s[1]), p2 = __expf(s[2]), p3 = __expf(s[3]);
                lpart[ht] += (p0 + p1) + (p2 + p3);
                bf16x2 pa = {(__bf16)p0, (__bf16)p1};
                bf16x2 pb = {(__bf16)p2, (__bf16)p3};
                int base = (ht * 16 + lr) * 40 + gt * 16 + quad * 4;
                *(bf16x2*)&sPw[base]     = pa;
                *(bf16x2*)&sPw[base + 2] = pb;
            }
        }
        bf16x8 paf[2];
#pragma unroll
        for (int ht = 0; ht < 2; ++ht)
            paf[ht] = *(const bf16x8*)&sPw[(ht * 16 + lr) * 40 + quad * 8];
#pragma unroll
        for (int dt = 0; dt < 4; ++dt) {
            bf16x8 vf = *(const bf16x8*)&sVf[((ch * 4 + quad) * 64 + dt * 16 + lr) * 8];
#pragma unroll
            for (int ht = 0; ht < 2; ++ht)
                O[ht][dt] = __builtin_amdgcn_mfma_f32_16x16x32_bf16(paf[ht], vf, O[ht][dt], 0, 0, 0);
        }
    }

    const float gm = gamma[0];
#pragma unroll
    for (int ht = 0; ht < 2; ++ht) {
        float l = lpart[ht];
        l += __shfl_xor(l, 16, 64);
        l += __shfl_xor(l, 32, 64);
        if (lane < 16) sL[wv * 32 + ht * 16 + lane] = gm / l;
    }

    // Scale O (C rows h = quad*4+i), stage bf16 per-wave, store coalesced.
#pragma unroll
    for (int ht = 0; ht < 2; ++ht) {
        float f0 = sL[wv * 32 + ht * 16 + quad * 4 + 0];
        float f1 = sL[wv * 32 + ht * 16 + quad * 4 + 1];
        float f2 = sL[wv * 32 + ht * 16 + quad * 4 + 2];
        float f3 = sL[wv * 32 + ht * 16 + quad * 4 + 3];
#pragma unroll
        for (int dt = 0; dt < 4; ++dt) {
            floatx4 o = O[ht][dt];
            int cb = dt * 16 + lr;
            *(__bf16*)&sPw[(quad * 4 + 0) * 72 + cb] = (__bf16)(o[0] * f0);
            *(__bf16*)&sPw[(quad * 4 + 1) * 72 + cb] = (__bf16)(o[1] * f1);
            *(__bf16*)&sPw[(quad * 4 + 2) * 72 + cb] = (__bf16)(o[2] * f2);
            *(__bf16*)&sPw[(quad * 4 + 3) * 72 + cb] = (__bf16)(o[3] * f3);
        }
#pragma unroll
        for (int it = 0; it < 2; ++it) {
            int idx = it * 64 + lane;
            int hr = idx >> 3, sg = idx & 7;
            uint4 v = *(const uint4*)&sPw[hr * 72 + sg * 8];
            *(uint4*)&Ob[(size_t)(col * HH + wv * 32 + ht * 16 + hr) * CC + sg * 8] = v;
        }
    }
}

// ===================== Kernel C: transpose + residual =====================
__global__ __launch_bounds__(256)
void add_kernel(const unsigned short* __restrict__ Ob,
                const float* __restrict__ x,
                float* __restrict__ out)
{
    __shared__ __align__(16) unsigned short sT[64 * 72];
    const int tid = threadIdx.x;
    const int bid = blockIdx.x;
    const int b = bid >> 11, rem = bid & 2047, h = rem >> 3, w0 = (rem & 7) << 6;

#pragma unroll
    for (int it = 0; it < 2; ++it) {
        int idx = it * 256 + tid;
        int tw = idx >> 3, sg = idx & 7;
        uint4 v = *(const uint4*)&Ob[(size_t)((b * WW + w0 + tw) * HH + h) * CC + sg * 8];
        *(uint4*)&sT[tw * 72 + sg * 8] = v;
    }
    __syncthreads();

    const int d = tid >> 2, ws = tid & 3;
    const size_t base = ((size_t)(b * CC + d)) * PLANE + h * WW + w0 + ws * 16;
    const float* xp = x + base;
    float* op = out + base;
#pragma unroll
    for (int k = 0; k < 4; ++k) {
        float4 xv = *(const float4*)&xp[k * 4];
        float4 r;
        r.x = bf2f(sT[(ws * 16 + k * 4 + 0) * 72 + d]) + xv.x;
        r.y = bf2f(sT[(ws * 16 + k * 4 + 1) * 72 + d]) + xv.y;
        r.z = bf2f(sT[(ws * 16 + k * 4 + 2) * 72 + d]) + xv.z;
        r.w = bf2f(sT[(ws * 16 + k * 4 + 3) * 72 + d]) + xv.w;
        *(float4*)&op[k * 4] = r;
    }
}

// ===================== Fallback: fused kernel (if ws too small) =====================
#define KSTR 40
#define VSTR 72
__device__ __forceinline__ float bflo(unsigned u) { union { unsigned v; float f; } x; x.v = u << 16; return x.f; }
__device__ __forceinline__ float bfhi(unsigned u) { union { unsigned v; float f; } x; x.v = u & 0xffff0000u; return x.f; }

__global__ __launch_bounds__(256, 1)
void vattn_fused(const float* __restrict__ x,
                 const float* __restrict__ Wq,
                 const float* __restrict__ bnq_g, const float* __restrict__ bnq_b,
                 const float* __restrict__ bnq_m, const float* __restrict__ bnq_v,
                 const float* __restrict__ Wk,
                 const float* __restrict__ bnk_g, const float* __restrict__ bnk_b,
                 const float* __restrict__ bnk_m, const float* __restrict__ bnk_v,
                 const float* __restrict__ Wv, const float* __restrict__ bv,
                 const float* __restrict__ gamma,
                 float* __restrict__ out)
{
    __shared__ __align__(16) __hip_bfloat16 sK[HH * KSTR];
    __shared__ __align__(16) __hip_bfloat16 sV2[HH * VSTR];
    const int t = threadIdx.x;
    const int bw = blockIdx.x;
    const int b = bw / WW, w = bw % WW;
    const size_t plane = (size_t)HH * WW;
    const float* xp = x + (size_t)b * CC * plane + (size_t)t * WW + w;
    float xr[CC];
#pragma unroll
    for (int c = 0; c < CC; ++c) xr[c] = xp[(size_t)c * plane];
    float qr[KCC];
#pragma unroll
    for (int j = 0; j < KCC; ++j) {
        float aq = 0.f, ak = 0.f;
#pragma unroll
        for (int c = 0; c < CC; ++c) { aq += Wq[j * CC + c] * xr[c]; ak += Wk[j * CC + c] * xr[c]; }
        const float sq = bnq_g[j] * rsqrtf(bnq_v[j] + 1e-5f);
        const float sk = bnk_g[j] * rsqrtf(bnk_v[j] + 1e-5f);
        qr[j] = (aq - bnq_m[j]) * sq + bnq_b[j];
        sK[t * KSTR + j] = __float2bfloat16((ak - bnk_m[j]) * sk + bnk_b[j]);
    }
#pragma unroll
    for (int d = 0; d < CC; ++d) {
        float av = bv[d];
#pragma unroll
        for (int c = 0; c < CC; ++c) av += Wv[d * CC + c] * xr[c];
        sV2[t * VSTR + d] = __float2bfloat16(av);
    }
    __syncthreads();
    float o[CC];
#pragma unroll
    for (int d = 0; d < CC; ++d) o[d] = 0.f;
    float l = 0.f;
    for (int g = 0; g < HH; ++g) {
        const uint4* kp = (const uint4*)(sK + g * KSTR);
        float s = 0.f;
#pragma unroll
        for (int i = 0; i < 4; ++i) {
            const uint4 kk = kp[i];
            s += bflo(kk.x) * qr[i * 8 + 0] + bfhi(kk.x) * qr[i * 8 + 1]
               + bflo(kk.y) * qr[i * 8 + 2] + bfhi(kk.y) * qr[i * 8 + 3]
               + bflo(kk.z) * qr[i * 8 + 4] + bfhi(kk.z) * qr[i * 8 + 5]
               + bflo(kk.w) * qr[i * 8 + 6] + bfhi(kk.w) * qr[i * 8 + 7];
        }
        const float p = __expf(s);
        l += p;
        const uint4* vp = (const uint4*)(sV2 + g * VSTR);
#pragma unroll
        for (int i = 0; i < 8; ++i) {
            const uint4 vv = vp[i];
            o[i * 8 + 0] += p * bflo(vv.x); o[i * 8 + 1] += p * bfhi(vv.x);
            o[i * 8 + 2] += p * bflo(vv.y); o[i * 8 + 3] += p * bfhi(vv.y);
            o[i * 8 + 4] += p * bflo(vv.z); o[i * 8 + 5] += p * bfhi(vv.z);
            o[i * 8 + 6] += p * bflo(vv.w); o[i * 8 + 7] += p * bfhi(vv.w);
        }
    }
    const float gm = gamma[0];
    const float rl = 1.f / l;
    float* op = out + (size_t)b * CC * plane + (size_t)t * WW + w;
#pragma unroll
    for (int d = 0; d < CC; ++d) op[(size_t)d * plane] = gm * (o[d] * rl) + xr[d];
}

extern "C" void kernel_launch(void* const* d_in, const int* in_sizes, int n_in,
                              void* d_out, int out_size, void* d_ws, size_t ws_size,
                              hipStream_t stream) {
    const float* x     = (const float*)d_in[0];
    const float* Wq    = (const float*)d_in[1];
    const float* bnq_g = (const float*)d_in[2];
    const float* bnq_b = (const float*)d_in[3];
    const float* bnq_m = (const float*)d_in[4];
    const float* bnq_v = (const float*)d_in[5];
    const float* Wk    = (const float*)d_in[6];
    const float* bnk_g = (const float*)d_in[7];
    const float* bnk_b = (const float*)d_in[8];
    const float* bnk_m = (const float*)d_in[9];
    const float* bnk_v = (const float*)d_in[10];
    const float* Wv    = (const float*)d_in[11];
    const float* bv    = (const float*)d_in[12];
    const float* gamma = (const float*)d_in[13];
    float* out = (float*)d_out;

    const size_t need = 201326592;   // Qb 32MB + Kb 32MB + Vb 64MB + Ob 64MB
    if (ws_size >= need) {
        unsigned short* Qb = (unsigned short*)d_ws;
        unsigned short* Kb = Qb + 16777216;
        unsigned short* Vb = Kb + 16777216;
        unsigned short* Ob = Vb + 33554432;
        hipLaunchKernelGGL(proj_kernel, dim3(512), dim3(512), 0, stream,
                           x, Wq, Wk, Wv, bv,
                           bnq_g, bnq_b, bnq_m, bnq_v,
                           bnk_g, bnk_b, bnk_m, bnk_v,
                           Qb, Kb, Vb);
        hipLaunchKernelGGL(attn_kernel, dim3(2048), dim3(512), 0, stream,
                           Qb, Kb, Vb, gamma, Ob);
        hipLaunchKernelGGL(add_kernel, dim3(8192), dim3(256), 0, stream,
                           Ob, x, out);
    } else {
        hipLaunchKernelGGL(vattn_fused, dim3(BB * WW), dim3(HH), 0, stream,
                           x, Wq, bnq_g, bnq_b, bnq_m, bnq_v,
                           Wk, bnk_g, bnk_b, bnk_m, bnk_v,
                           Wv, bv, gamma, out);
    }
}